// Round 28
// baseline (92.908 us; speedup 1.0000x reference)
//
#include <hip/hip_runtime.h>

#define BB 4
#define NN 16384
#define EE 65536
#define CC 256
#define MM 64

// ws float offsets
#define WS_NORM   0                  // B*M (atomics, zeroed by kPP block 256)
#define WS_T1     256
#define WS_ESN    512
#define WS_BCOMB  768                // 64
#define WS_ITX    832                // 64
#define WS_ITE    896                // 64
#define WS_WES2   1024               // legacy
#define WS_WCOMB  5120               // W_comb^T bf16 [64][256] u16
#define WS_WES2T  13312              // Wes2^T bf16 [64][64] u16
#define WS_SW2    21504              // bf16 SW2 [B*N*M u16] (8MB)
#define WS_SSUM   WS_SW2             // after kEN2, overlaid by Ssum [B*M*C floats]
#define WS_SPART  4215808            // B*PB*M*C partials

typedef __attribute__((ext_vector_type(8))) __bf16 bf16x8_t;
typedef __attribute__((ext_vector_type(4))) float f32x4_t;

static __device__ __forceinline__ unsigned short f2bf(float f) {
    unsigned int u = __float_as_uint(f);
    unsigned int r = (u + 0x7FFFu + ((u >> 16) & 1u)) >> 16;   // RNE
    return (unsigned short)r;
}
static __device__ __forceinline__ float bf2f(unsigned short h) {
    return __uint_as_float((unsigned int)h << 16);
}
static __device__ __forceinline__ unsigned int pk2(float a, float b) {
    return (unsigned int)f2bf(a) | ((unsigned int)f2bf(b) << 16);
}

// ---------- PP: merged preamble + accumulator zeroing (r18 proven) ----------
__global__ __launch_bounds__(256) void kPP(const float* __restrict__ Wx,
                                           const float* __restrict__ Wsl,
                                           const float* __restrict__ bx,
                                           const float* __restrict__ phx,
                                           const float* __restrict__ bsl,
                                           const float* __restrict__ tx,
                                           const float* __restrict__ te,
                                           const float* __restrict__ Wes,
                                           float* __restrict__ ws) {
    __shared__ float row[256];
    __shared__ float part[4][64];
    const int tid = threadIdx.x;
    const int m = tid & 63, kq = tid >> 6;
    if (blockIdx.x < 256) {
        const int c = blockIdx.x;
        row[tid] = Wx[c * CC + tid];
        __syncthreads();
        float acc = 0.f;
#pragma unroll 8
        for (int kk = 0; kk < 64; ++kk) {
            int k = kq * 64 + kk;
            acc += row[k] * Wsl[k * MM + m];
        }
        part[kq][m] = acc;
        __syncthreads();
        if (tid < 64) {
            float v = part[0][tid] + part[1][tid] + part[2][tid] + part[3][tid];
            ((unsigned short*)(ws + WS_WCOMB))[tid * 256 + c] = f2bf(v);
        }
    } else {
#pragma unroll
        for (int i = 0; i < 3; ++i) ws[i * 256 + tid] = 0.f;
        row[tid] = bx[tid] + phx[tid];
        __syncthreads();
        float acc = 0.f;
#pragma unroll 8
        for (int kk = 0; kk < 64; ++kk) {
            int k = kq * 64 + kk;
            acc += row[k] * Wsl[k * MM + m];
        }
        part[kq][m] = acc;
        __syncthreads();
        if (tid < 64) {
            ws[WS_BCOMB + tid] = bsl[tid] +
                part[0][tid] + part[1][tid] + part[2][tid] + part[3][tid];
            ws[WS_ITX + tid] = 1.f / fminf(fmaxf(tx[tid], 0.01f), 5.f);
            ws[WS_ITE + tid] = 1.f / fminf(fmaxf(te[tid], 0.01f), 5.f);
        }
        unsigned short* w2t = (unsigned short*)(ws + WS_WES2T);
#pragma unroll
        for (int i = 0; i < 16; ++i) {
            int e = i * 256 + tid;
            int m2 = e >> 6, k2 = e & 63;
            float itk = 1.f / fminf(fmaxf(te[k2], 0.01f), 5.f);
            w2t[m2 * 64 + k2] = f2bf(itk * Wes[k2 * 64 + m2]);
        }
    }
}

// ---------- N1: MFMA x@W_comb (software-pipelined) -> softmax -> sw + norm
//             + MFMA sw@Wes2 -> sw2b (EXACT r23 form) ----------
#define N1_STEP(CQ, Q0, Q1, Q2, Q3)                                             \
    {                                                                           \
        bf16x8_t bfr_[4];                                                       \
        _Pragma("unroll")                                                       \
        for (int mt = 0; mt < 4; ++mt)                                          \
            bfr_[mt] = *(const bf16x8_t*)&smem_u[(mt * 16 + ln) * 264 + (CQ) + kg * 8]; \
        union { unsigned short u[8]; bf16x8_t v; } af0_, af1_;                  \
        af0_.u[0]=f2bf(Q0.x); af0_.u[1]=f2bf(Q0.y); af0_.u[2]=f2bf(Q0.z); af0_.u[3]=f2bf(Q0.w); \
        af0_.u[4]=f2bf(Q1.x); af0_.u[5]=f2bf(Q1.y); af0_.u[6]=f2bf(Q1.z); af0_.u[7]=f2bf(Q1.w); \
        af1_.u[0]=f2bf(Q2.x); af1_.u[1]=f2bf(Q2.y); af1_.u[2]=f2bf(Q2.z); af1_.u[3]=f2bf(Q2.w); \
        af1_.u[4]=f2bf(Q3.x); af1_.u[5]=f2bf(Q3.y); af1_.u[6]=f2bf(Q3.z); af1_.u[7]=f2bf(Q3.w); \
        _Pragma("unroll")                                                       \
        for (int mt = 0; mt < 4; ++mt) {                                        \
            acc[0][mt] = __builtin_amdgcn_mfma_f32_16x16x32_bf16(af0_.v, bfr_[mt], acc[0][mt], 0, 0, 0); \
            acc[1][mt] = __builtin_amdgcn_mfma_f32_16x16x32_bf16(af1_.v, bfr_[mt], acc[1][mt], 0, 0, 0); \
        }                                                                       \
    }

__global__ __launch_bounds__(256, 2) void kN1(const float* __restrict__ x,
                                              const float* __restrict__ ws,
                                              float* __restrict__ out1,
                                              unsigned short* __restrict__ sw2b,
                                              float* __restrict__ norm_acc) {
    __shared__ float smem[17920];    // 71.7 KB
    __shared__ float redn[4][64];
    __shared__ float bcs[64], itxs[64];
    unsigned short* smem_u = (unsigned short*)smem;
    float* swl = smem + 4096;
    const int tid = threadIdx.x;
    const int wv = tid >> 6, l = tid & 63;
    const int ln = l & 15, kg = l >> 4;
    const int row0 = blockIdx.x * 128;
    const int b = blockIdx.x >> 7;
    const int r = tid >> 2;
    const int h = tid & 3;

    if (tid < 64) { bcs[tid] = ws[WS_BCOMB + tid]; itxs[tid] = ws[WS_ITX + tid]; }

    const unsigned short* wct = (const unsigned short*)(ws + WS_WCOMB);
#pragma unroll
    for (int i = 0; i < 8; ++i) {
        int f8 = (i * 256 + tid) * 8;
        int m = f8 >> 8, k = f8 & 255;
        *(uint4*)&smem_u[m * 264 + k] = *(const uint4*)&wct[f8];
    }
    __syncthreads();

    f32x4_t acc[2][4];
#pragma unroll
    for (int i = 0; i < 2; ++i)
#pragma unroll
        for (int j = 0; j < 4; ++j) acc[i][j] = (f32x4_t){0.f, 0.f, 0.f, 0.f};

    const float* bp0 = x + (size_t)(row0 + (wv * 2 + 0) * 16 + ln) * CC + kg * 8;
    const float* bp1 = x + (size_t)(row0 + (wv * 2 + 1) * 16 + ln) * CC + kg * 8;
    float4 A0 = *(const float4*)(bp0), A1 = *(const float4*)(bp0 + 4);
    float4 A2 = *(const float4*)(bp1), A3 = *(const float4*)(bp1 + 4);
    for (int c0 = 0; c0 < CC; c0 += 64) {
        float4 B0 = *(const float4*)(bp0 + c0 + 32), B1 = *(const float4*)(bp0 + c0 + 36);
        float4 B2 = *(const float4*)(bp1 + c0 + 32), B3 = *(const float4*)(bp1 + c0 + 36);
        N1_STEP(c0, A0, A1, A2, A3);
        if (c0 + 64 < CC) {
            A0 = *(const float4*)(bp0 + c0 + 64); A1 = *(const float4*)(bp0 + c0 + 68);
            A2 = *(const float4*)(bp1 + c0 + 64); A3 = *(const float4*)(bp1 + c0 + 68);
        }
        N1_STEP(c0 + 32, B0, B1, B2, B3);
    }
    __syncthreads();

#pragma unroll
    for (int rt = 0; rt < 2; ++rt)
#pragma unroll
        for (int mt = 0; mt < 4; ++mt)
#pragma unroll
            for (int j = 0; j < 4; ++j)
                swl[((wv * 2 + rt) * 16 + kg * 4 + j) * 68 + mt * 16 + ln] =
                    acc[rt][mt][j];
    {
        const unsigned short* w2tg = (const unsigned short*)(ws + WS_WES2T);
        int m2 = tid >> 2, k2 = (tid & 3) * 16;
        *(uint4*)&smem_u[m2 * 80 + k2] = *(const uint4*)&w2tg[m2 * 64 + k2];
        *(uint4*)&smem_u[m2 * 80 + k2 + 8] = *(const uint4*)&w2tg[m2 * 64 + k2 + 8];
    }
    __syncthreads();

    float sacc[2][16];
#pragma unroll
    for (int i = 0; i < 2; ++i)
#pragma unroll
        for (int q = 0; q < 4; ++q) {
            float4 v = *(float4*)&swl[(r + 64 * i) * 68 + h * 16 + q * 4];
            sacc[i][q * 4 + 0] = v.x; sacc[i][q * 4 + 1] = v.y;
            sacc[i][q * 4 + 2] = v.z; sacc[i][q * 4 + 3] = v.w;
        }
    float colsum[16];
#pragma unroll
    for (int j = 0; j < 16; ++j) colsum[j] = 0.f;
#pragma unroll
    for (int i = 0; i < 2; ++i) {
        float mx = -1e30f;
#pragma unroll
        for (int j = 0; j < 16; ++j) {
            int m = h * 16 + j;
            sacc[i][j] = (sacc[i][j] + bcs[m]) * itxs[m];
            mx = fmaxf(mx, sacc[i][j]);
        }
        mx = fmaxf(mx, __shfl_xor(mx, 1));
        mx = fmaxf(mx, __shfl_xor(mx, 2));
        float s = 0.f;
#pragma unroll
        for (int j = 0; j < 16; ++j) { sacc[i][j] = __expf(sacc[i][j] - mx); s += sacc[i][j]; }
        s += __shfl_xor(s, 1);
        s += __shfl_xor(s, 2);
        float inv = 1.f / s;
        int rl = r + 64 * i;
        int row = row0 + rl;
#pragma unroll
        for (int q = 0; q < 4; ++q) {
            float4 v = {sacc[i][q * 4 + 0] * inv, sacc[i][q * 4 + 1] * inv,
                        sacc[i][q * 4 + 2] * inv, sacc[i][q * 4 + 3] * inv};
            *(float4*)(out1 + (size_t)row * MM + h * 16 + q * 4) = v;
            *(float4*)&swl[rl * 68 + h * 16 + q * 4] = v;
#pragma unroll
            for (int j = 0; j < 4; ++j) colsum[q * 4 + j] += ((float*)&v)[j];
        }
    }
#pragma unroll
    for (int j = 0; j < 16; ++j) {
        colsum[j] += __shfl_xor(colsum[j], 4);
        colsum[j] += __shfl_xor(colsum[j], 8);
        colsum[j] += __shfl_xor(colsum[j], 16);
        colsum[j] += __shfl_xor(colsum[j], 32);
    }
    if (l < 4) {
#pragma unroll
        for (int j = 0; j < 16; ++j) redn[wv][h * 16 + j] = colsum[j];
    }
    __syncthreads();

    f32x4_t eacc[2][4];
#pragma unroll
    for (int i = 0; i < 2; ++i)
#pragma unroll
        for (int j = 0; j < 4; ++j) eacc[i][j] = (f32x4_t){0.f, 0.f, 0.f, 0.f};
#pragma unroll
    for (int ks = 0; ks < 2; ++ks) {
        bf16x8_t bfw[4];
#pragma unroll
        for (int mt = 0; mt < 4; ++mt)
            bfw[mt] = *(const bf16x8_t*)&smem_u[(mt * 16 + ln) * 80 + ks * 32 + kg * 8];
#pragma unroll
        for (int rt = 0; rt < 2; ++rt) {
            const float* ap = &swl[((wv * 2 + rt) * 16 + ln) * 68 + ks * 32 + kg * 8];
            float4 p0 = *(const float4*)ap;
            float4 p1 = *(const float4*)(ap + 4);
            union { unsigned short u[8]; bf16x8_t v; } af;
            af.u[0] = f2bf(p0.x); af.u[1] = f2bf(p0.y);
            af.u[2] = f2bf(p0.z); af.u[3] = f2bf(p0.w);
            af.u[4] = f2bf(p1.x); af.u[5] = f2bf(p1.y);
            af.u[6] = f2bf(p1.z); af.u[7] = f2bf(p1.w);
#pragma unroll
            for (int mt = 0; mt < 4; ++mt)
                eacc[rt][mt] = __builtin_amdgcn_mfma_f32_16x16x32_bf16(
                    af.v, bfw[mt], eacc[rt][mt], 0, 0, 0);
        }
    }
    {
        unsigned short* esb = (unsigned short*)(smem + 12800);
#pragma unroll
        for (int rt = 0; rt < 2; ++rt)
#pragma unroll
            for (int mt = 0; mt < 4; ++mt)
#pragma unroll
                for (int j = 0; j < 4; ++j)
                    esb[((wv * 2 + rt) * 16 + kg * 4 + j) * 80 + mt * 16 + ln] =
                        f2bf(eacc[rt][mt][j]);
    }
    __syncthreads();
    {
        const unsigned short* esb = (const unsigned short*)(smem + 12800);
        int row = tid >> 1, half = tid & 1;
        const uint4* src = (const uint4*)&esb[row * 80 + half * 32];
        uint4* dst = (uint4*)(sw2b + (size_t)(row0 + row) * MM + half * 32);
        dst[0] = src[0]; dst[1] = src[1]; dst[2] = src[2]; dst[3] = src[3];
    }

    if (tid < 64)
        atomicAdd(&norm_acc[b * MM + tid],
                  redn[0][tid] + redn[1][tid] + redn[2][tid] + redn[3][tid]);
}

// ---------- EN2: grid-fused MFMA-kN2 (T14 prefetch, r27) + kE ----------
// r28: single knob — launch_bounds hint 4 -> 5 (VGPR cap ~102 >> 56 live set;
// LDS 20.7KB x5 fits). One more block/CU of latency hiding on both branches.
__global__ __launch_bounds__(256, 5) void kEN2(const float* __restrict__ x,
                                               const float* __restrict__ sw,
                                               float* __restrict__ Spart,
                                               int PB, int rowsPB, int nb2,
                                               const float* __restrict__ eattr,
                                               const int* __restrict__ eidx,
                                               const unsigned short* __restrict__ sw2b,
                                               const float* __restrict__ bes,
                                               float* __restrict__ t1_acc,
                                               float* __restrict__ esn_acc) {
    __shared__ float smem[5184];   // 20.7 KB union
    const int tid = threadIdx.x;
    if ((int)blockIdx.x < nb2) {
        unsigned short* xT = (unsigned short*)smem;
        unsigned short* sT = (unsigned short*)(smem + 2560);
        const int bid = blockIdx.x;
        const int ch = bid & 1;
        const int p = (bid >> 1) % PB, b = (bid >> 1) / PB;
        const int base = b * NN + p * rowsPB;
        const int wv = tid >> 6, l = tid & 63;
        const int ln = l & 15, kg = l >> 4;
        const int ct0 = wv * 2;

        const int ra0 = 2 * (tid >> 5), cq0 = (tid & 31) * 4;
        const int key0 = (cq0 >> 2) & 3;
        const int off0 = ((ra0 >> 3) ^ key0) * 8 + (ra0 & 7);
        const int ra1 = ra0 + 16;
        const int off1 = ((ra1 >> 3) ^ key0) * 8 + (ra1 & 7);
        const int ras = 2 * (tid >> 4), mqs = (tid & 15) * 4;
        const int keys = (mqs >> 2) & 3;
        const int offs = ((ras >> 3) ^ keys) * 8 + (ras & 7);

        f32x4_t acc[2][4];   // [ct][mt]
#pragma unroll
        for (int i = 0; i < 2; ++i)
#pragma unroll
            for (int j = 0; j < 4; ++j) acc[i][j] = (f32x4_t){0.f, 0.f, 0.f, 0.f};

        float4 xa0, xb0, xa1, xb1, sva, svb;
#define KN2_LOAD(R0)                                                            \
        {                                                                       \
            const float* xp0 = x + (size_t)(base + (R0) + ra0) * CC + ch * 128 + cq0; \
            xa0 = *(const float4*)xp0; xb0 = *(const float4*)(xp0 + CC);        \
            const float* xp1 = xp0 + 16 * CC;                                   \
            xa1 = *(const float4*)xp1; xb1 = *(const float4*)(xp1 + CC);        \
            const float* sp = sw + (size_t)(base + (R0) + ras) * MM + mqs;      \
            sva = *(const float4*)sp; svb = *(const float4*)(sp + MM);          \
        }
        KN2_LOAD(0);
        for (int r0 = 0; r0 < rowsPB; r0 += 32) {
            __syncthreads();
            *(unsigned int*)&xT[(cq0 + 0) * 40 + off0] = pk2(xa0.x, xb0.x);
            *(unsigned int*)&xT[(cq0 + 1) * 40 + off0] = pk2(xa0.y, xb0.y);
            *(unsigned int*)&xT[(cq0 + 2) * 40 + off0] = pk2(xa0.z, xb0.z);
            *(unsigned int*)&xT[(cq0 + 3) * 40 + off0] = pk2(xa0.w, xb0.w);
            *(unsigned int*)&xT[(cq0 + 0) * 40 + off1] = pk2(xa1.x, xb1.x);
            *(unsigned int*)&xT[(cq0 + 1) * 40 + off1] = pk2(xa1.y, xb1.y);
            *(unsigned int*)&xT[(cq0 + 2) * 40 + off1] = pk2(xa1.z, xb1.z);
            *(unsigned int*)&xT[(cq0 + 3) * 40 + off1] = pk2(xa1.w, xb1.w);
            *(unsigned int*)&sT[(mqs + 0) * 40 + offs] = pk2(sva.x, svb.x);
            *(unsigned int*)&sT[(mqs + 1) * 40 + offs] = pk2(sva.y, svb.y);
            *(unsigned int*)&sT[(mqs + 2) * 40 + offs] = pk2(sva.z, svb.z);
            *(unsigned int*)&sT[(mqs + 3) * 40 + offs] = pk2(sva.w, svb.w);
            if (r0 + 32 < rowsPB) KN2_LOAD(r0 + 32);
            __syncthreads();
            bf16x8_t afr[4];
#pragma unroll
            for (int mt = 0; mt < 4; ++mt) {
                int m = mt * 16 + ln;
                int chunk = kg ^ ((m >> 2) & 3);
                afr[mt] = *(const bf16x8_t*)&sT[m * 40 + chunk * 8];
            }
#pragma unroll
            for (int ct = 0; ct < 2; ++ct) {
                int c = (ct0 + ct) * 16 + ln;
                int chunk = kg ^ ((c >> 2) & 3);
                bf16x8_t bfr = *(const bf16x8_t*)&xT[c * 40 + chunk * 8];
#pragma unroll
                for (int mt = 0; mt < 4; ++mt)
                    acc[ct][mt] = __builtin_amdgcn_mfma_f32_16x16x32_bf16(
                        afr[mt], bfr, acc[ct][mt], 0, 0, 0);
            }
        }
#undef KN2_LOAD
        float* dst = Spart + (size_t)(b * PB + p) * MM * CC + ch * 128;
#pragma unroll
        for (int ct = 0; ct < 2; ++ct)
#pragma unroll
            for (int mt = 0; mt < 4; ++mt)
#pragma unroll
                for (int j = 0; j < 4; ++j) {
                    int m = mt * 16 + kg * 4 + j;
                    int c = (ct0 + ct) * 16 + ln;
                    dst[(size_t)m * CC + c] = acc[ct][mt][j];
                }
    } else {
        unsigned short* uu = (unsigned short*)smem;
        float* eav  = smem + 4352;
        float* redt = smem + 4608;
        float* redn = smem + 4864;
        float* bes_s = smem + 5120;
        const int w = tid >> 6, l = tid & 63;
        const int eg = ((int)blockIdx.x - nb2) * 256 + tid;
        const int b = eg >> 16;
        if (tid < 64) bes_s[tid] = bes[tid];
        const int2 idx = ((const int2*)eidx)[eg];
        const float ea = eattr[eg];
        const uint4* g0 = (const uint4*)(sw2b + (size_t)(b * NN + idx.x) * MM);
        const uint4* g1 = (const uint4*)(sw2b + (size_t)(b * NN + idx.y) * MM);
        eav[w * 64 + l] = ea;
        __syncthreads();

        float v[64];
#pragma unroll
        for (int q = 0; q < 8; ++q) {
            uint4 a = g0[q], c = g1[q];
            unsigned int au[4] = {a.x, a.y, a.z, a.w};
            unsigned int cu[4] = {c.x, c.y, c.z, c.w};
#pragma unroll
            for (int j = 0; j < 4; ++j) {
                int m = q * 8 + j * 2;
                v[m + 0] = __uint_as_float(au[j] << 16) + __uint_as_float(cu[j] << 16) + bes_s[m + 0];
                v[m + 1] = __uint_as_float(au[j] & 0xFFFF0000u) + __uint_as_float(cu[j] & 0xFFFF0000u) + bes_s[m + 1];
            }
        }
        float mx = -1e30f;
#pragma unroll
        for (int m = 0; m < 64; ++m) mx = fmaxf(mx, v[m]);
        float s = 0.f;
#pragma unroll
        for (int m = 0; m < 64; ++m) { v[m] = __expf(v[m] - mx); s += v[m]; }
        float inv = 1.f / s;

        const int ml = l & 31, rh = l >> 5;
#pragma unroll
        for (int ph = 0; ph < 2; ++ph) {
            __syncthreads();
#pragma unroll
            for (int j = 0; j < 32; j += 2)
                *(unsigned int*)&uu[w * 2176 + l * 34 + j] =
                    pk2(v[ph * 32 + j] * inv, v[ph * 32 + j + 1] * inv);
            __syncthreads();
            float t = 0.f, n = 0.f;
#pragma unroll 8
            for (int rr = 0; rr < 32; ++rr) {
                int r = rh * 32 + rr;
                float e = bf2f(uu[w * 2176 + r * 34 + ml]);
                n += e;
                t += e * eav[w * 64 + r];
            }
            t += __shfl_xor(t, 32);
            n += __shfl_xor(n, 32);
            if (l < 32) { redt[w * 64 + ph * 32 + l] = t; redn[w * 64 + ph * 32 + l] = n; }
        }
        __syncthreads();
        if (tid < 64) {
            atomicAdd(&t1_acc[b * 64 + tid],
                      redt[tid] + redt[64 + tid] + redt[128 + tid] + redt[192 + tid]);
            atomicAdd(&esn_acc[b * 64 + tid],
                      redn[tid] + redn[64 + tid] + redn[128 + tid] + redn[192 + tid]);
        }
    }
}

// ---------- R: parallel partial reduce Spart -> Ssum [B,M,C] ----------
__global__ __launch_bounds__(256) void kR(const float* __restrict__ Spart,
                                          float* __restrict__ Ssum, int PB) {
    const int idx = blockIdx.x * 256 + threadIdx.x;
    const int b = idx >> 14;
    const int mc = idx & 16383;
    const float* sp = Spart + (size_t)b * PB * MM * CC + mc;
    float a0 = 0.f, a1 = 0.f, a2 = 0.f, a3 = 0.f;
    for (int p = 0; p < PB; p += 4) {
        a0 += sp[(size_t)(p + 0) * MM * CC];
        a1 += sp[(size_t)(p + 1) * MM * CC];
        a2 += sp[(size_t)(p + 2) * MM * CC];
        a3 += sp[(size_t)(p + 3) * MM * CC];
    }
    Ssum[idx] = (a0 + a1) + (a2 + a3);
}

// ---------- F2: matvec + combine -> slice_token ----------
__global__ __launch_bounds__(256) void kF2(const float* __restrict__ ws,
                                           const float* __restrict__ Wfx,
                                           const float* __restrict__ bfx,
                                           const float* __restrict__ Wfe,
                                           const float* __restrict__ bfe,
                                           const float* __restrict__ phe,
                                           float* __restrict__ out0) {
    __shared__ float srow[256];
    const int bid = blockIdx.x;
    const int b = bid >> 6, m = bid & 63;
    const int t = threadIdx.x;
    srow[t] = ws[WS_SSUM + (size_t)(b * MM + m) * CC + t];
    __syncthreads();
    float acc = 0.f;
#pragma unroll 8
    for (int k = 0; k < 256; ++k) acc += srow[k] * Wfx[k * CC + t];
    float nv  = ws[WS_NORM + b * 64 + m];
    float t1v = ws[WS_T1   + b * 64 + m];
    float ev  = ws[WS_ESN  + b * 64 + m];
    const float scale = (float)NN / (float)EE;   // 0.25
    float num = acc + nv * bfx[t] + scale * (t1v * Wfe[t] + ev * (bfe[t] + phe[t]));
    float den = nv + scale * ev + 1e-5f;
    out0[(size_t)(b * MM + m) * CC + t] = num / den;
}

extern "C" void kernel_launch(void* const* d_in, const int* in_sizes, int n_in,
                              void* d_out, int out_size, void* d_ws, size_t ws_size,
                              hipStream_t stream) {
    const float* x     = (const float*)d_in[0];
    const float* eattr = (const float*)d_in[1];
    const int*   eidx  = (const int*)d_in[2];
    const float* Wfx   = (const float*)d_in[3];
    const float* bfx   = (const float*)d_in[4];
    const float* Wx    = (const float*)d_in[5];
    const float* bx    = (const float*)d_in[6];
    const float* Wsl   = (const float*)d_in[7];
    const float* bsl   = (const float*)d_in[8];
    const float* tx    = (const float*)d_in[9];
    const float* phx   = (const float*)d_in[10];
    const float* Wfe   = (const float*)d_in[11];
    const float* bfe   = (const float*)d_in[12];
    const float* te    = (const float*)d_in[13];
    const float* Wes   = (const float*)d_in[14];
    const float* bes   = (const float*)d_in[15];
    const float* phe   = (const float*)d_in[16];

    float* out0 = (float*)d_out;                  // slice_token [B,M,C]
    float* out1 = out0 + (size_t)BB * MM * CC;    // slice_weight [B,N,M]
    float* ws   = (float*)d_ws;
    unsigned short* sw2b = (unsigned short*)(ws + WS_SW2);

    int PB = 32;
    while (PB > 8) {
        size_t need = (size_t)(WS_SPART + (size_t)BB * PB * MM * CC) * sizeof(float);
        if (need <= ws_size) break;
        PB >>= 1;
    }
    int rowsPB = NN / PB;
    int nb2 = BB * PB * 2;

    kPP<<<257, 256, 0, stream>>>(Wx, Wsl, bx, phx, bsl, tx, te, Wes, ws);
    kN1<<<512, 256, 0, stream>>>(x, ws, out1, sw2b, ws + WS_NORM);
    kEN2<<<nb2 + EE * BB / 256, 256, 0, stream>>>(x, out1, ws + WS_SPART, PB, rowsPB, nb2,
                                                  eattr, eidx, sw2b, bes,
                                                  ws + WS_T1, ws + WS_ESN);
    kR <<<1024, 256, 0, stream>>>(ws + WS_SPART, ws + WS_SSUM, PB);
    kF2<<<256, 256, 0, stream>>>(ws, Wfx, bfx, Wfe, bfe, phe, out0);
}

// Round 29
// 88.307 us; speedup vs baseline: 1.0521x; 1.0521x over previous
//
#include <hip/hip_runtime.h>

#define BB 4
#define NN 16384
#define EE 65536
#define CC 256
#define MM 64

// ws float offsets
#define WS_NORM   0                  // B*M (atomics, zeroed by kPP block 256)
#define WS_T1     256
#define WS_ESN    512
#define WS_BCOMB  768                // 64
#define WS_ITX    832                // 64
#define WS_ITE    896                // 64
#define WS_WES2   1024               // legacy
#define WS_WCOMB  5120               // W_comb^T bf16 [64][256] u16
#define WS_WES2T  13312              // Wes2^T bf16 [64][64] u16
#define WS_SW2    21504              // bf16 SW2 [B*N*M u16] (8MB)
#define WS_SSUM   WS_SW2             // after kEN2, overlaid by Ssum [B*M*C floats]
#define WS_SPART  4215808            // B*PB*M*C partials

typedef __attribute__((ext_vector_type(8))) __bf16 bf16x8_t;
typedef __attribute__((ext_vector_type(4))) float f32x4_t;

static __device__ __forceinline__ unsigned short f2bf(float f) {
    unsigned int u = __float_as_uint(f);
    unsigned int r = (u + 0x7FFFu + ((u >> 16) & 1u)) >> 16;   // RNE
    return (unsigned short)r;
}
static __device__ __forceinline__ float bf2f(unsigned short h) {
    return __uint_as_float((unsigned int)h << 16);
}
static __device__ __forceinline__ unsigned int pk2(float a, float b) {
    return (unsigned int)f2bf(a) | ((unsigned int)f2bf(b) << 16);
}

// ---------- PP: merged preamble + accumulator zeroing (r18 proven) ----------
__global__ __launch_bounds__(256) void kPP(const float* __restrict__ Wx,
                                           const float* __restrict__ Wsl,
                                           const float* __restrict__ bx,
                                           const float* __restrict__ phx,
                                           const float* __restrict__ bsl,
                                           const float* __restrict__ tx,
                                           const float* __restrict__ te,
                                           const float* __restrict__ Wes,
                                           float* __restrict__ ws) {
    __shared__ float row[256];
    __shared__ float part[4][64];
    const int tid = threadIdx.x;
    const int m = tid & 63, kq = tid >> 6;
    if (blockIdx.x < 256) {
        const int c = blockIdx.x;
        row[tid] = Wx[c * CC + tid];
        __syncthreads();
        float acc = 0.f;
#pragma unroll 8
        for (int kk = 0; kk < 64; ++kk) {
            int k = kq * 64 + kk;
            acc += row[k] * Wsl[k * MM + m];
        }
        part[kq][m] = acc;
        __syncthreads();
        if (tid < 64) {
            float v = part[0][tid] + part[1][tid] + part[2][tid] + part[3][tid];
            ((unsigned short*)(ws + WS_WCOMB))[tid * 256 + c] = f2bf(v);
        }
    } else {
#pragma unroll
        for (int i = 0; i < 3; ++i) ws[i * 256 + tid] = 0.f;
        row[tid] = bx[tid] + phx[tid];
        __syncthreads();
        float acc = 0.f;
#pragma unroll 8
        for (int kk = 0; kk < 64; ++kk) {
            int k = kq * 64 + kk;
            acc += row[k] * Wsl[k * MM + m];
        }
        part[kq][m] = acc;
        __syncthreads();
        if (tid < 64) {
            ws[WS_BCOMB + tid] = bsl[tid] +
                part[0][tid] + part[1][tid] + part[2][tid] + part[3][tid];
            ws[WS_ITX + tid] = 1.f / fminf(fmaxf(tx[tid], 0.01f), 5.f);
            ws[WS_ITE + tid] = 1.f / fminf(fmaxf(te[tid], 0.01f), 5.f);
        }
        unsigned short* w2t = (unsigned short*)(ws + WS_WES2T);
#pragma unroll
        for (int i = 0; i < 16; ++i) {
            int e = i * 256 + tid;
            int m2 = e >> 6, k2 = e & 63;
            float itk = 1.f / fminf(fmaxf(te[k2], 0.01f), 5.f);
            w2t[m2 * 64 + k2] = f2bf(itk * Wes[k2 * 64 + m2]);
        }
    }
}

// ---------- N1: MFMA x@W_comb (software-pipelined) -> softmax -> sw + norm
//             + MFMA sw@Wes2 -> sw2b (EXACT r23 form) ----------
#define N1_STEP(CQ, Q0, Q1, Q2, Q3)                                             \
    {                                                                           \
        bf16x8_t bfr_[4];                                                       \
        _Pragma("unroll")                                                       \
        for (int mt = 0; mt < 4; ++mt)                                          \
            bfr_[mt] = *(const bf16x8_t*)&smem_u[(mt * 16 + ln) * 264 + (CQ) + kg * 8]; \
        union { unsigned short u[8]; bf16x8_t v; } af0_, af1_;                  \
        af0_.u[0]=f2bf(Q0.x); af0_.u[1]=f2bf(Q0.y); af0_.u[2]=f2bf(Q0.z); af0_.u[3]=f2bf(Q0.w); \
        af0_.u[4]=f2bf(Q1.x); af0_.u[5]=f2bf(Q1.y); af0_.u[6]=f2bf(Q1.z); af0_.u[7]=f2bf(Q1.w); \
        af1_.u[0]=f2bf(Q2.x); af1_.u[1]=f2bf(Q2.y); af1_.u[2]=f2bf(Q2.z); af1_.u[3]=f2bf(Q2.w); \
        af1_.u[4]=f2bf(Q3.x); af1_.u[5]=f2bf(Q3.y); af1_.u[6]=f2bf(Q3.z); af1_.u[7]=f2bf(Q3.w); \
        _Pragma("unroll")                                                       \
        for (int mt = 0; mt < 4; ++mt) {                                        \
            acc[0][mt] = __builtin_amdgcn_mfma_f32_16x16x32_bf16(af0_.v, bfr_[mt], acc[0][mt], 0, 0, 0); \
            acc[1][mt] = __builtin_amdgcn_mfma_f32_16x16x32_bf16(af1_.v, bfr_[mt], acc[1][mt], 0, 0, 0); \
        }                                                                       \
    }

__global__ __launch_bounds__(256, 2) void kN1(const float* __restrict__ x,
                                              const float* __restrict__ ws,
                                              float* __restrict__ out1,
                                              unsigned short* __restrict__ sw2b,
                                              float* __restrict__ norm_acc) {
    __shared__ float smem[17920];    // 71.7 KB
    __shared__ float redn[4][64];
    __shared__ float bcs[64], itxs[64];
    unsigned short* smem_u = (unsigned short*)smem;
    float* swl = smem + 4096;
    const int tid = threadIdx.x;
    const int wv = tid >> 6, l = tid & 63;
    const int ln = l & 15, kg = l >> 4;
    const int row0 = blockIdx.x * 128;
    const int b = blockIdx.x >> 7;
    const int r = tid >> 2;
    const int h = tid & 3;

    if (tid < 64) { bcs[tid] = ws[WS_BCOMB + tid]; itxs[tid] = ws[WS_ITX + tid]; }

    const unsigned short* wct = (const unsigned short*)(ws + WS_WCOMB);
#pragma unroll
    for (int i = 0; i < 8; ++i) {
        int f8 = (i * 256 + tid) * 8;
        int m = f8 >> 8, k = f8 & 255;
        *(uint4*)&smem_u[m * 264 + k] = *(const uint4*)&wct[f8];
    }
    __syncthreads();

    f32x4_t acc[2][4];
#pragma unroll
    for (int i = 0; i < 2; ++i)
#pragma unroll
        for (int j = 0; j < 4; ++j) acc[i][j] = (f32x4_t){0.f, 0.f, 0.f, 0.f};

    const float* bp0 = x + (size_t)(row0 + (wv * 2 + 0) * 16 + ln) * CC + kg * 8;
    const float* bp1 = x + (size_t)(row0 + (wv * 2 + 1) * 16 + ln) * CC + kg * 8;
    float4 A0 = *(const float4*)(bp0), A1 = *(const float4*)(bp0 + 4);
    float4 A2 = *(const float4*)(bp1), A3 = *(const float4*)(bp1 + 4);
    for (int c0 = 0; c0 < CC; c0 += 64) {
        float4 B0 = *(const float4*)(bp0 + c0 + 32), B1 = *(const float4*)(bp0 + c0 + 36);
        float4 B2 = *(const float4*)(bp1 + c0 + 32), B3 = *(const float4*)(bp1 + c0 + 36);
        N1_STEP(c0, A0, A1, A2, A3);
        if (c0 + 64 < CC) {
            A0 = *(const float4*)(bp0 + c0 + 64); A1 = *(const float4*)(bp0 + c0 + 68);
            A2 = *(const float4*)(bp1 + c0 + 64); A3 = *(const float4*)(bp1 + c0 + 68);
        }
        N1_STEP(c0 + 32, B0, B1, B2, B3);
    }
    __syncthreads();

#pragma unroll
    for (int rt = 0; rt < 2; ++rt)
#pragma unroll
        for (int mt = 0; mt < 4; ++mt)
#pragma unroll
            for (int j = 0; j < 4; ++j)
                swl[((wv * 2 + rt) * 16 + kg * 4 + j) * 68 + mt * 16 + ln] =
                    acc[rt][mt][j];
    {
        const unsigned short* w2tg = (const unsigned short*)(ws + WS_WES2T);
        int m2 = tid >> 2, k2 = (tid & 3) * 16;
        *(uint4*)&smem_u[m2 * 80 + k2] = *(const uint4*)&w2tg[m2 * 64 + k2];
        *(uint4*)&smem_u[m2 * 80 + k2 + 8] = *(const uint4*)&w2tg[m2 * 64 + k2 + 8];
    }
    __syncthreads();

    float sacc[2][16];
#pragma unroll
    for (int i = 0; i < 2; ++i)
#pragma unroll
        for (int q = 0; q < 4; ++q) {
            float4 v = *(float4*)&swl[(r + 64 * i) * 68 + h * 16 + q * 4];
            sacc[i][q * 4 + 0] = v.x; sacc[i][q * 4 + 1] = v.y;
            sacc[i][q * 4 + 2] = v.z; sacc[i][q * 4 + 3] = v.w;
        }
    float colsum[16];
#pragma unroll
    for (int j = 0; j < 16; ++j) colsum[j] = 0.f;
#pragma unroll
    for (int i = 0; i < 2; ++i) {
        float mx = -1e30f;
#pragma unroll
        for (int j = 0; j < 16; ++j) {
            int m = h * 16 + j;
            sacc[i][j] = (sacc[i][j] + bcs[m]) * itxs[m];
            mx = fmaxf(mx, sacc[i][j]);
        }
        mx = fmaxf(mx, __shfl_xor(mx, 1));
        mx = fmaxf(mx, __shfl_xor(mx, 2));
        float s = 0.f;
#pragma unroll
        for (int j = 0; j < 16; ++j) { sacc[i][j] = __expf(sacc[i][j] - mx); s += sacc[i][j]; }
        s += __shfl_xor(s, 1);
        s += __shfl_xor(s, 2);
        float inv = 1.f / s;
        int rl = r + 64 * i;
        int row = row0 + rl;
#pragma unroll
        for (int q = 0; q < 4; ++q) {
            float4 v = {sacc[i][q * 4 + 0] * inv, sacc[i][q * 4 + 1] * inv,
                        sacc[i][q * 4 + 2] * inv, sacc[i][q * 4 + 3] * inv};
            *(float4*)(out1 + (size_t)row * MM + h * 16 + q * 4) = v;
            *(float4*)&swl[rl * 68 + h * 16 + q * 4] = v;
#pragma unroll
            for (int j = 0; j < 4; ++j) colsum[q * 4 + j] += ((float*)&v)[j];
        }
    }
#pragma unroll
    for (int j = 0; j < 16; ++j) {
        colsum[j] += __shfl_xor(colsum[j], 4);
        colsum[j] += __shfl_xor(colsum[j], 8);
        colsum[j] += __shfl_xor(colsum[j], 16);
        colsum[j] += __shfl_xor(colsum[j], 32);
    }
    if (l < 4) {
#pragma unroll
        for (int j = 0; j < 16; ++j) redn[wv][h * 16 + j] = colsum[j];
    }
    __syncthreads();

    f32x4_t eacc[2][4];
#pragma unroll
    for (int i = 0; i < 2; ++i)
#pragma unroll
        for (int j = 0; j < 4; ++j) eacc[i][j] = (f32x4_t){0.f, 0.f, 0.f, 0.f};
#pragma unroll
    for (int ks = 0; ks < 2; ++ks) {
        bf16x8_t bfw[4];
#pragma unroll
        for (int mt = 0; mt < 4; ++mt)
            bfw[mt] = *(const bf16x8_t*)&smem_u[(mt * 16 + ln) * 80 + ks * 32 + kg * 8];
#pragma unroll
        for (int rt = 0; rt < 2; ++rt) {
            const float* ap = &swl[((wv * 2 + rt) * 16 + ln) * 68 + ks * 32 + kg * 8];
            float4 p0 = *(const float4*)ap;
            float4 p1 = *(const float4*)(ap + 4);
            union { unsigned short u[8]; bf16x8_t v; } af;
            af.u[0] = f2bf(p0.x); af.u[1] = f2bf(p0.y);
            af.u[2] = f2bf(p0.z); af.u[3] = f2bf(p0.w);
            af.u[4] = f2bf(p1.x); af.u[5] = f2bf(p1.y);
            af.u[6] = f2bf(p1.z); af.u[7] = f2bf(p1.w);
#pragma unroll
            for (int mt = 0; mt < 4; ++mt)
                eacc[rt][mt] = __builtin_amdgcn_mfma_f32_16x16x32_bf16(
                    af.v, bfw[mt], eacc[rt][mt], 0, 0, 0);
        }
    }
    {
        unsigned short* esb = (unsigned short*)(smem + 12800);
#pragma unroll
        for (int rt = 0; rt < 2; ++rt)
#pragma unroll
            for (int mt = 0; mt < 4; ++mt)
#pragma unroll
                for (int j = 0; j < 4; ++j)
                    esb[((wv * 2 + rt) * 16 + kg * 4 + j) * 80 + mt * 16 + ln] =
                        f2bf(eacc[rt][mt][j]);
    }
    __syncthreads();
    {
        const unsigned short* esb = (const unsigned short*)(smem + 12800);
        int row = tid >> 1, half = tid & 1;
        const uint4* src = (const uint4*)&esb[row * 80 + half * 32];
        uint4* dst = (uint4*)(sw2b + (size_t)(row0 + row) * MM + half * 32);
        dst[0] = src[0]; dst[1] = src[1]; dst[2] = src[2]; dst[3] = src[3];
    }

    if (tid < 64)
        atomicAdd(&norm_acc[b * MM + tid],
                  redn[0][tid] + redn[1][tid] + redn[2][tid] + redn[3][tid]);
}

// ---------- EN2: grid-fused MFMA-kN2 (T14 prefetch, r27 proven) + kE ----------
__global__ __launch_bounds__(256, 4) void kEN2(const float* __restrict__ x,
                                               const float* __restrict__ sw,
                                               float* __restrict__ Spart,
                                               int PB, int rowsPB, int nb2,
                                               const float* __restrict__ eattr,
                                               const int* __restrict__ eidx,
                                               const unsigned short* __restrict__ sw2b,
                                               const float* __restrict__ bes,
                                               float* __restrict__ t1_acc,
                                               float* __restrict__ esn_acc) {
    __shared__ float smem[5184];   // 20.7 KB union
    const int tid = threadIdx.x;
    if ((int)blockIdx.x < nb2) {
        unsigned short* xT = (unsigned short*)smem;
        unsigned short* sT = (unsigned short*)(smem + 2560);
        const int bid = blockIdx.x;
        const int ch = bid & 1;
        const int p = (bid >> 1) % PB, b = (bid >> 1) / PB;
        const int base = b * NN + p * rowsPB;
        const int wv = tid >> 6, l = tid & 63;
        const int ln = l & 15, kg = l >> 4;
        const int ct0 = wv * 2;

        const int ra0 = 2 * (tid >> 5), cq0 = (tid & 31) * 4;
        const int key0 = (cq0 >> 2) & 3;
        const int off0 = ((ra0 >> 3) ^ key0) * 8 + (ra0 & 7);
        const int ra1 = ra0 + 16;
        const int off1 = ((ra1 >> 3) ^ key0) * 8 + (ra1 & 7);
        const int ras = 2 * (tid >> 4), mqs = (tid & 15) * 4;
        const int keys = (mqs >> 2) & 3;
        const int offs = ((ras >> 3) ^ keys) * 8 + (ras & 7);

        f32x4_t acc[2][4];   // [ct][mt]
#pragma unroll
        for (int i = 0; i < 2; ++i)
#pragma unroll
            for (int j = 0; j < 4; ++j) acc[i][j] = (f32x4_t){0.f, 0.f, 0.f, 0.f};

        float4 xa0, xb0, xa1, xb1, sva, svb;
#define KN2_LOAD(R0)                                                            \
        {                                                                       \
            const float* xp0 = x + (size_t)(base + (R0) + ra0) * CC + ch * 128 + cq0; \
            xa0 = *(const float4*)xp0; xb0 = *(const float4*)(xp0 + CC);        \
            const float* xp1 = xp0 + 16 * CC;                                   \
            xa1 = *(const float4*)xp1; xb1 = *(const float4*)(xp1 + CC);        \
            const float* sp = sw + (size_t)(base + (R0) + ras) * MM + mqs;      \
            sva = *(const float4*)sp; svb = *(const float4*)(sp + MM);          \
        }
        KN2_LOAD(0);
        for (int r0 = 0; r0 < rowsPB; r0 += 32) {
            __syncthreads();
            *(unsigned int*)&xT[(cq0 + 0) * 40 + off0] = pk2(xa0.x, xb0.x);
            *(unsigned int*)&xT[(cq0 + 1) * 40 + off0] = pk2(xa0.y, xb0.y);
            *(unsigned int*)&xT[(cq0 + 2) * 40 + off0] = pk2(xa0.z, xb0.z);
            *(unsigned int*)&xT[(cq0 + 3) * 40 + off0] = pk2(xa0.w, xb0.w);
            *(unsigned int*)&xT[(cq0 + 0) * 40 + off1] = pk2(xa1.x, xb1.x);
            *(unsigned int*)&xT[(cq0 + 1) * 40 + off1] = pk2(xa1.y, xb1.y);
            *(unsigned int*)&xT[(cq0 + 2) * 40 + off1] = pk2(xa1.z, xb1.z);
            *(unsigned int*)&xT[(cq0 + 3) * 40 + off1] = pk2(xa1.w, xb1.w);
            *(unsigned int*)&sT[(mqs + 0) * 40 + offs] = pk2(sva.x, svb.x);
            *(unsigned int*)&sT[(mqs + 1) * 40 + offs] = pk2(sva.y, svb.y);
            *(unsigned int*)&sT[(mqs + 2) * 40 + offs] = pk2(sva.z, svb.z);
            *(unsigned int*)&sT[(mqs + 3) * 40 + offs] = pk2(sva.w, svb.w);
            if (r0 + 32 < rowsPB) KN2_LOAD(r0 + 32);
            __syncthreads();
            bf16x8_t afr[4];
#pragma unroll
            for (int mt = 0; mt < 4; ++mt) {
                int m = mt * 16 + ln;
                int chunk = kg ^ ((m >> 2) & 3);
                afr[mt] = *(const bf16x8_t*)&sT[m * 40 + chunk * 8];
            }
#pragma unroll
            for (int ct = 0; ct < 2; ++ct) {
                int c = (ct0 + ct) * 16 + ln;
                int chunk = kg ^ ((c >> 2) & 3);
                bf16x8_t bfr = *(const bf16x8_t*)&xT[c * 40 + chunk * 8];
#pragma unroll
                for (int mt = 0; mt < 4; ++mt)
                    acc[ct][mt] = __builtin_amdgcn_mfma_f32_16x16x32_bf16(
                        afr[mt], bfr, acc[ct][mt], 0, 0, 0);
            }
        }
#undef KN2_LOAD
        float* dst = Spart + (size_t)(b * PB + p) * MM * CC + ch * 128;
#pragma unroll
        for (int ct = 0; ct < 2; ++ct)
#pragma unroll
            for (int mt = 0; mt < 4; ++mt)
#pragma unroll
                for (int j = 0; j < 4; ++j) {
                    int m = mt * 16 + kg * 4 + j;
                    int c = (ct0 + ct) * 16 + ln;
                    dst[(size_t)m * CC + c] = acc[ct][mt][j];
                }
    } else {
        unsigned short* uu = (unsigned short*)smem;
        float* eav  = smem + 4352;
        float* redt = smem + 4608;
        float* redn = smem + 4864;
        float* bes_s = smem + 5120;
        const int w = tid >> 6, l = tid & 63;
        const int eg = ((int)blockIdx.x - nb2) * 256 + tid;
        const int b = eg >> 16;
        if (tid < 64) bes_s[tid] = bes[tid];
        const int2 idx = ((const int2*)eidx)[eg];
        const float ea = eattr[eg];
        const uint4* g0 = (const uint4*)(sw2b + (size_t)(b * NN + idx.x) * MM);
        const uint4* g1 = (const uint4*)(sw2b + (size_t)(b * NN + idx.y) * MM);
        eav[w * 64 + l] = ea;
        __syncthreads();

        float v[64];
#pragma unroll
        for (int q = 0; q < 8; ++q) {
            uint4 a = g0[q], c = g1[q];
            unsigned int au[4] = {a.x, a.y, a.z, a.w};
            unsigned int cu[4] = {c.x, c.y, c.z, c.w};
#pragma unroll
            for (int j = 0; j < 4; ++j) {
                int m = q * 8 + j * 2;
                v[m + 0] = __uint_as_float(au[j] << 16) + __uint_as_float(cu[j] << 16) + bes_s[m + 0];
                v[m + 1] = __uint_as_float(au[j] & 0xFFFF0000u) + __uint_as_float(cu[j] & 0xFFFF0000u) + bes_s[m + 1];
            }
        }
        float mx = -1e30f;
#pragma unroll
        for (int m = 0; m < 64; ++m) mx = fmaxf(mx, v[m]);
        float s = 0.f;
#pragma unroll
        for (int m = 0; m < 64; ++m) { v[m] = __expf(v[m] - mx); s += v[m]; }
        float inv = 1.f / s;

        const int ml = l & 31, rh = l >> 5;
#pragma unroll
        for (int ph = 0; ph < 2; ++ph) {
            __syncthreads();
#pragma unroll
            for (int j = 0; j < 32; j += 2)
                *(unsigned int*)&uu[w * 2176 + l * 34 + j] =
                    pk2(v[ph * 32 + j] * inv, v[ph * 32 + j + 1] * inv);
            __syncthreads();
            float t = 0.f, n = 0.f;
#pragma unroll 8
            for (int rr = 0; rr < 32; ++rr) {
                int r = rh * 32 + rr;
                float e = bf2f(uu[w * 2176 + r * 34 + ml]);
                n += e;
                t += e * eav[w * 64 + r];
            }
            t += __shfl_xor(t, 32);
            n += __shfl_xor(n, 32);
            if (l < 32) { redt[w * 64 + ph * 32 + l] = t; redn[w * 64 + ph * 32 + l] = n; }
        }
        __syncthreads();
        if (tid < 64) {
            atomicAdd(&t1_acc[b * 64 + tid],
                      redt[tid] + redt[64 + tid] + redt[128 + tid] + redt[192 + tid]);
            atomicAdd(&esn_acc[b * 64 + tid],
                      redn[tid] + redn[64 + tid] + redn[128 + tid] + redn[192 + tid]);
        }
    }
}

// ---------- R: parallel partial reduce Spart -> Ssum [B,M,C] ----------
__global__ __launch_bounds__(256) void kR(const float* __restrict__ Spart,
                                          float* __restrict__ Ssum, int PB) {
    const int idx = blockIdx.x * 256 + threadIdx.x;
    const int b = idx >> 14;
    const int mc = idx & 16383;
    const float* sp = Spart + (size_t)b * PB * MM * CC + mc;
    float a0 = 0.f, a1 = 0.f, a2 = 0.f, a3 = 0.f;
    for (int p = 0; p < PB; p += 4) {
        a0 += sp[(size_t)(p + 0) * MM * CC];
        a1 += sp[(size_t)(p + 1) * MM * CC];
        a2 += sp[(size_t)(p + 2) * MM * CC];
        a3 += sp[(size_t)(p + 3) * MM * CC];
    }
    Ssum[idx] = (a0 + a1) + (a2 + a3);
}

// ---------- F2: matvec + combine -> slice_token ----------
__global__ __launch_bounds__(256) void kF2(const float* __restrict__ ws,
                                           const float* __restrict__ Wfx,
                                           const float* __restrict__ bfx,
                                           const float* __restrict__ Wfe,
                                           const float* __restrict__ bfe,
                                           const float* __restrict__ phe,
                                           float* __restrict__ out0) {
    __shared__ float srow[256];
    const int bid = blockIdx.x;
    const int b = bid >> 6, m = bid & 63;
    const int t = threadIdx.x;
    srow[t] = ws[WS_SSUM + (size_t)(b * MM + m) * CC + t];
    __syncthreads();
    float acc = 0.f;
#pragma unroll 8
    for (int k = 0; k < 256; ++k) acc += srow[k] * Wfx[k * CC + t];
    float nv  = ws[WS_NORM + b * 64 + m];
    float t1v = ws[WS_T1   + b * 64 + m];
    float ev  = ws[WS_ESN  + b * 64 + m];
    const float scale = (float)NN / (float)EE;   // 0.25
    float num = acc + nv * bfx[t] + scale * (t1v * Wfe[t] + ev * (bfe[t] + phe[t]));
    float den = nv + scale * ev + 1e-5f;
    out0[(size_t)(b * MM + m) * CC + t] = num / den;
}

extern "C" void kernel_launch(void* const* d_in, const int* in_sizes, int n_in,
                              void* d_out, int out_size, void* d_ws, size_t ws_size,
                              hipStream_t stream) {
    const float* x     = (const float*)d_in[0];
    const float* eattr = (const float*)d_in[1];
    const int*   eidx  = (const int*)d_in[2];
    const float* Wfx   = (const float*)d_in[3];
    const float* bfx   = (const float*)d_in[4];
    const float* Wx    = (const float*)d_in[5];
    const float* bx    = (const float*)d_in[6];
    const float* Wsl   = (const float*)d_in[7];
    const float* bsl   = (const float*)d_in[8];
    const float* tx    = (const float*)d_in[9];
    const float* phx   = (const float*)d_in[10];
    const float* Wfe   = (const float*)d_in[11];
    const float* bfe   = (const float*)d_in[12];
    const float* te    = (const float*)d_in[13];
    const float* Wes   = (const float*)d_in[14];
    const float* bes   = (const float*)d_in[15];
    const float* phe   = (const float*)d_in[16];

    float* out0 = (float*)d_out;                  // slice_token [B,M,C]
    float* out1 = out0 + (size_t)BB * MM * CC;    // slice_weight [B,N,M]
    float* ws   = (float*)d_ws;
    unsigned short* sw2b = (unsigned short*)(ws + WS_SW2);

    int PB = 32;
    while (PB > 8) {
        size_t need = (size_t)(WS_SPART + (size_t)BB * PB * MM * CC) * sizeof(float);
        if (need <= ws_size) break;
        PB >>= 1;
    }
    int rowsPB = NN / PB;
    int nb2 = BB * PB * 2;

    kPP<<<257, 256, 0, stream>>>(Wx, Wsl, bx, phx, bsl, tx, te, Wes, ws);
    kN1<<<512, 256, 0, stream>>>(x, ws, out1, sw2b, ws + WS_NORM);
    kEN2<<<nb2 + EE * BB / 256, 256, 0, stream>>>(x, out1, ws + WS_SPART, PB, rowsPB, nb2,
                                                  eattr, eidx, sw2b, bes,
                                                  ws + WS_T1, ws + WS_ESN);
    kR <<<1024, 256, 0, stream>>>(ws + WS_SPART, ws + WS_SSUM, PB);
    kF2<<<256, 256, 0, stream>>>(ws, Wfx, bfx, Wfe, bfe, phe, out0);
}